// Round 4
// baseline (13726.906 us; speedup 1.0000x reference)
//
#include <hip/hip_runtime.h>
#include <math.h>

// LSTM B=128,T=1024,D=64,H=256,C=6 — sync-free weight-stationary kernel.
// 128 wgs x 1024 threads, one wg per batch (1 wg/CU; 128 CUs active).
// Thread (u=tid>>2, ks=tid&3) owns unit u's 4 gate cols, k-quarter ks.
// Weights in registers as packed f16 pairs: 4 cols x (64 Wh + 16 Wx) = 160 VGPRs.
// Inner loop: v_dot2_f32_f16 (fp32 accum). shfl_xor(1),(2) -> all 4 lanes get
// full preacts for unit u -> redundant (bit-identical) activation + c/h update.
// h stored f16 in LDS, ks-padded (144B quarter stride) -> conflict-free reads.
// R3 lesson: __launch_bounds__(1024,4) capped VGPR at 64 and spilled the
// weights; now (1024,1). No cross-wg sync (agent-scope RT was ~6us/step).

#define Tt 1024
#define Dd 64
#define Hh 256
#define G4 1024
#define Cc 6

typedef _Float16 f16x2 __attribute__((ext_vector_type(2)));

__device__ __forceinline__ float dot2(f16x2 a, f16x2 b, float c) {
#if __has_builtin(__builtin_amdgcn_fdot2)
    return __builtin_amdgcn_fdot2(a, b, c, false);
#else
    return c + (float)a.x * (float)b.x + (float)a.y * (float)b.y;
#endif
}

__device__ __forceinline__ float sigm(float p) {
    return 1.0f / (1.0f + __expf(-p));
}
__device__ __forceinline__ float tanh_fast(float p) {
    // 1 - 2/(e^2p + 1); stable: p->-inf: 1-2/1=-1; p->+inf: e^2p=inf -> 1-0=1
    return 1.0f - 2.0f / (__expf(2.0f * p) + 1.0f);
}

__global__ __launch_bounds__(1024, 1) void lstm_reg(
    const float* __restrict__ x,     // [B,T,D]
    const float* __restrict__ Wx,    // [D,4H]
    const float* __restrict__ Wh,    // [H,4H]
    const float* __restrict__ bias,  // [4H]
    const float* __restrict__ Wout,  // [H,C]
    const float* __restrict__ bout,  // [C]
    float* __restrict__ out)         // [B,T,C]
{
    // LDS: ks-quarter-padded layouts (conflict-free 4-distinct-address reads)
    __shared__ alignas(16) unsigned short h_lds[4][72];     // h[64ks+i] at [ks][i], 144B stride
    __shared__ alignas(16) unsigned short x_lds[2][4][24];  // x[16ks+i] at [par][ks][i], 48B stride
    __shared__ float wout_t[Cc][Hh];
    __shared__ float bout_l[Cc];

    const int tid = threadIdx.x;
    const int b   = blockIdx.x;
    const int u   = tid >> 2;   // unit 0..255
    const int ks  = tid & 3;    // k-quarter

    // ---- prologue: weights -> f16 pairs in registers ----
    f16x2 wh[4][32];   // [col q][k-pair]  (k = 64*ks + 2j, 2j+1)
    f16x2 wxr[4][8];   // [col q][k-pair]  (k = 16*ks + 2j, 2j+1)
    float bq[4];
    #pragma unroll
    for (int q = 0; q < 4; ++q) {
        const int col = u + 256 * q;
        #pragma unroll
        for (int j = 0; j < 32; ++j) {
            float w0 = Wh[(64 * ks + 2 * j) * G4 + col];
            float w1 = Wh[(64 * ks + 2 * j + 1) * G4 + col];
            wh[q][j] = f16x2{(_Float16)w0, (_Float16)w1};
        }
        #pragma unroll
        for (int j = 0; j < 8; ++j) {
            float w0 = Wx[(16 * ks + 2 * j) * G4 + col];
            float w1 = Wx[(16 * ks + 2 * j + 1) * G4 + col];
            wxr[q][j] = f16x2{(_Float16)w0, (_Float16)w1};
        }
        bq[q] = bias[col];
    }

    if (tid < 288) ((unsigned short*)h_lds)[tid] = 0;  // h(-1) = 0
    for (int i = tid; i < Cc * Hh; i += 1024) wout_t[i % Cc][i / Cc] = Wout[i];
    if (tid < Cc) bout_l[tid] = bout[tid];
    const float* xB = x + (long)b * Tt * Dd;
    if (tid >= 960) {  // stage x(0) as f16
        int d = tid - 960;
        _Float16 xv = (_Float16)xB[d];
        x_lds[0][d >> 4][d & 15] = __builtin_bit_cast(unsigned short, xv);
    }
    float c_state = 0.0f;
    __syncthreads();

    // ---- time loop ----
    for (int t = 0; t < Tt; ++t) {
        const int par = t & 1;

        // issue next x load early (hide HBM latency under the dots)
        float x_next = 0.0f;
        const bool xload = (tid >= 960) && (t + 1 < Tt);
        if (xload) x_next = xB[(long)(t + 1) * Dd + (tid - 960)];

        // phase A: partial dots over this thread's k-quarter, 4 cols
        float a0 = 0.f, a1 = 0.f, a2 = 0.f, a3 = 0.f;
        {
            const float4* hq = (const float4*)((const char*)h_lds + 144 * ks);
            #pragma unroll
            for (int j = 0; j < 8; ++j) {
                float4 hv = hq[j];
                f16x2 h0 = __builtin_bit_cast(f16x2, hv.x);
                f16x2 h1 = __builtin_bit_cast(f16x2, hv.y);
                f16x2 h2 = __builtin_bit_cast(f16x2, hv.z);
                f16x2 h3 = __builtin_bit_cast(f16x2, hv.w);
                a0 = dot2(h0, wh[0][4*j+0], a0); a0 = dot2(h1, wh[0][4*j+1], a0);
                a0 = dot2(h2, wh[0][4*j+2], a0); a0 = dot2(h3, wh[0][4*j+3], a0);
                a1 = dot2(h0, wh[1][4*j+0], a1); a1 = dot2(h1, wh[1][4*j+1], a1);
                a1 = dot2(h2, wh[1][4*j+2], a1); a1 = dot2(h3, wh[1][4*j+3], a1);
                a2 = dot2(h0, wh[2][4*j+0], a2); a2 = dot2(h1, wh[2][4*j+1], a2);
                a2 = dot2(h2, wh[2][4*j+2], a2); a2 = dot2(h3, wh[2][4*j+3], a2);
                a3 = dot2(h0, wh[3][4*j+0], a3); a3 = dot2(h1, wh[3][4*j+1], a3);
                a3 = dot2(h2, wh[3][4*j+2], a3); a3 = dot2(h3, wh[3][4*j+3], a3);
            }
            const float4* xq = (const float4*)((const char*)x_lds[par] + 48 * ks);
            #pragma unroll
            for (int j = 0; j < 2; ++j) {
                float4 xv = xq[j];
                f16x2 x0 = __builtin_bit_cast(f16x2, xv.x);
                f16x2 x1 = __builtin_bit_cast(f16x2, xv.y);
                f16x2 x2 = __builtin_bit_cast(f16x2, xv.z);
                f16x2 x3 = __builtin_bit_cast(f16x2, xv.w);
                a0 = dot2(x0, wxr[0][4*j+0], a0); a0 = dot2(x1, wxr[0][4*j+1], a0);
                a0 = dot2(x2, wxr[0][4*j+2], a0); a0 = dot2(x3, wxr[0][4*j+3], a0);
                a1 = dot2(x0, wxr[1][4*j+0], a1); a1 = dot2(x1, wxr[1][4*j+1], a1);
                a1 = dot2(x2, wxr[1][4*j+2], a1); a1 = dot2(x3, wxr[1][4*j+3], a1);
                a2 = dot2(x0, wxr[2][4*j+0], a2); a2 = dot2(x1, wxr[2][4*j+1], a2);
                a2 = dot2(x2, wxr[2][4*j+2], a2); a2 = dot2(x3, wxr[2][4*j+3], a2);
                a3 = dot2(x0, wxr[3][4*j+0], a3); a3 = dot2(x1, wxr[3][4*j+1], a3);
                a3 = dot2(x2, wxr[3][4*j+2], a3); a3 = dot2(x3, wxr[3][4*j+3], a3);
            }
        }
        // cross-ks reduce within 4-lane groups -> all lanes get full sums
        a0 += __shfl_xor(a0, 1); a0 += __shfl_xor(a0, 2);
        a1 += __shfl_xor(a1, 1); a1 += __shfl_xor(a1, 2);
        a2 += __shfl_xor(a2, 1); a2 += __shfl_xor(a2, 2);
        a3 += __shfl_xor(a3, 1); a3 += __shfl_xor(a3, 2);

        // activation + state update (redundant in 4 lanes, bit-identical)
        float ig = sigm(a0 + bq[0]);
        float fg = sigm(a1 + bq[1]);
        float gg = tanh_fast(a2 + bq[2]);
        float og = sigm(a3 + bq[3]);
        c_state = fg * c_state + ig * gg;
        float hval = og * tanh_fast(c_state);

        __syncthreads();  // B1: all waves done reading h(t-1)/x(t)

        if (ks == 0) {
            _Float16 hf = (_Float16)hval;
            h_lds[u >> 6][u & 63] = __builtin_bit_cast(unsigned short, hf);
        }
        if (xload) {
            int d = tid - 960;
            _Float16 xv = (_Float16)x_next;
            x_lds[par ^ 1][d >> 4][d & 15] = __builtin_bit_cast(unsigned short, xv);
        }
        __syncthreads();  // B2: h(t), x(t+1) staged

        // phase C: output projection for step t (waves 0..5); overlaps with
        // other waves starting step t+1 (h_lds next written after B1(t+1)).
        const int w = tid >> 6, l = tid & 63;
        if (w < Cc) {
            float p = 0.0f;
            #pragma unroll
            for (int j = 0; j < 4; ++j) {
                unsigned short hu = h_lds[j][l];
                _Float16 hf = __builtin_bit_cast(_Float16, hu);
                p += (float)hf * wout_t[w][l + 64 * j];
            }
            #pragma unroll
            for (int off = 32; off > 0; off >>= 1) p += __shfl_down(p, off);
            if (l == 0) out[((long)b * Tt + t) * Cc + w] = p + bout_l[w];
        }
    }
}

extern "C" void kernel_launch(void* const* d_in, const int* in_sizes, int n_in,
                              void* d_out, int out_size, void* d_ws, size_t ws_size,
                              hipStream_t stream) {
    const float* x    = (const float*)d_in[0];
    const float* Wx   = (const float*)d_in[1];
    const float* Wh   = (const float*)d_in[2];
    const float* bvec = (const float*)d_in[3];
    const float* Wout = (const float*)d_in[4];
    const float* bout = (const float*)d_in[5];
    float* outp = (float*)d_out;

    lstm_reg<<<dim3(128), dim3(1024), 0, stream>>>(x, Wx, Wh, bvec, Wout, bout, outp);
}

// Round 5
// 6939.996 us; speedup vs baseline: 1.9779x; 1.9779x over previous
//
#include <hip/hip_runtime.h>
#include <math.h>

// LSTM B=128,T=1024,D=64,H=256,C=6 — pair-split weight-stationary kernel.
// 256 blocks x 512 threads (8 waves = 2 waves/SIMD -> 256 VGPR cap).
// Pair (bid, bid^8) = one batch; block `half` owns units 128*half..+127,
// ALL 4 gates, ALL 256 k -> exact preacts, no partial exchange.
// Thread (u_loc=tid>>2, ks=tid&3): 4 gate cols of unit u, k-quarter ks.
// Weights f16x2 in regs: 4x32 (Wh) + 4x8 (Wx) = 160 VGPRs.
// Per step: dots -> shfl_xor reduce -> redundant c/h update -> exchange
// h-half (256 B) with partner via d_ws (release/acquire flags, parity dbuf).
// R4 lesson: 1024-thr blocks hard-cap at 128 VGPR (512-reg pool / 4 waves
// per SIMD) -> silent spill. 512-thr blocks + (512,2) give 256 cap.

#define Tt 1024
#define Dd 64
#define Hh 256
#define G4 1024
#define Cc 6
// ws: [0,1024) int flags[128][2]; [1024,...) ushort hx[128][2][2][128]
#define WS_NEED (1024 + 128*2*2*128*2)

typedef _Float16 f16x2 __attribute__((ext_vector_type(2)));

__device__ __forceinline__ float dot2(f16x2 a, f16x2 b, float c) {
#if __has_builtin(__builtin_amdgcn_fdot2)
    return __builtin_amdgcn_fdot2(a, b, c, false);
#else
    return c + (float)a.x * (float)b.x + (float)a.y * (float)b.y;
#endif
}
__device__ __forceinline__ float sigm(float p) { return 1.0f / (1.0f + __expf(-p)); }
__device__ __forceinline__ float tanh_fast(float p) {
    return 1.0f - 2.0f / (__expf(2.0f * p) + 1.0f);
}

__global__ void zero_flags(int* flags) {
    if (threadIdx.x < 256) flags[threadIdx.x] = 0;
}

__global__ __launch_bounds__(512, 2) void lstm_pair(
    const float* __restrict__ x, const float* __restrict__ Wx,
    const float* __restrict__ Wh, const float* __restrict__ bias,
    const float* __restrict__ Wout, const float* __restrict__ bout,
    float* __restrict__ out, int* __restrict__ flags,
    unsigned short* __restrict__ hx)
{
    __shared__ alignas(16) unsigned short h_lds[4][72];     // h[64q+i] at [q][i] (144B stride)
    __shared__ alignas(16) unsigned short x_lds[2][4][24];  // x[16q+i] at [par][q][i]
    __shared__ float wout_t[Cc][Hh];
    __shared__ float bout_l[Cc];

    const int tid  = threadIdx.x;
    const int bid  = blockIdx.x;
    const int xcd  = bid & 7;
    const int slot = bid >> 3;
    const int half = slot & 1;                 // unit-half owned by this block
    const int g    = xcd * 16 + (slot >> 1);   // batch / pair id, 0..127

    const int u_loc = tid >> 2;                // 0..127
    const int ks    = tid & 3;                 // k-quarter
    const int u     = 128 * half + u_loc;      // global unit

    int* flg = flags + g * 2;
    unsigned short* hxg = hx + g * 512;        // [par][half][128]

    // ---- prologue: weights -> f16x2 registers ----
    f16x2 wh[4][32];   // [gate q][k-pair], k = 64ks+2j
    f16x2 wxr[4][8];   // [gate q][k-pair], k = 16ks+2j
    float bq[4];
    #pragma unroll
    for (int q = 0; q < 4; ++q) {
        const int col = 256 * q + u;
        #pragma unroll
        for (int j = 0; j < 32; ++j) {
            float w0 = Wh[(64 * ks + 2 * j) * G4 + col];
            float w1 = Wh[(64 * ks + 2 * j + 1) * G4 + col];
            wh[q][j] = f16x2{(_Float16)w0, (_Float16)w1};
        }
        #pragma unroll
        for (int j = 0; j < 8; ++j) {
            float w0 = Wx[(16 * ks + 2 * j) * G4 + col];
            float w1 = Wx[(16 * ks + 2 * j + 1) * G4 + col];
            wxr[q][j] = f16x2{(_Float16)w0, (_Float16)w1};
        }
        bq[q] = bias[col];
    }

    if (tid < 288) ((unsigned short*)h_lds)[tid] = 0;   // h(-1) = 0
    for (int i = tid; i < Cc * Hh; i += 512) wout_t[i % Cc][i / Cc] = Wout[i];
    if (tid < Cc) bout_l[tid] = bout[tid];
    const float* xB = x + (long)g * Tt * Dd;
    if (tid >= 448) {                                    // stage x(0) as f16
        int d = tid - 448;
        _Float16 xv = (_Float16)xB[d];
        x_lds[0][d >> 4][d & 15] = __builtin_bit_cast(unsigned short, xv);
    }
    float c_state = 0.0f;
    __syncthreads();

    // ---- time loop ----
    for (int t = 0; t < Tt; ++t) {
        const int par = t & 1;

        // issue next-x load early (HBM latency hides under dots)
        float x_next = 0.0f;
        const bool xload = (tid >= 448) && (t + 1 < Tt);
        if (xload) x_next = xB[(long)(t + 1) * Dd + (tid - 448)];

        // phase A: exact dots for this thread's 4 gate cols, k-quarter ks
        float a0 = 0.f, a1 = 0.f, a2 = 0.f, a3 = 0.f;
        {
            const float4* hq = (const float4*)((const char*)h_lds + 144 * ks);
            #pragma unroll
            for (int j = 0; j < 8; ++j) {
                float4 hv = hq[j];
                f16x2 h0 = __builtin_bit_cast(f16x2, hv.x);
                f16x2 h1 = __builtin_bit_cast(f16x2, hv.y);
                f16x2 h2 = __builtin_bit_cast(f16x2, hv.z);
                f16x2 h3 = __builtin_bit_cast(f16x2, hv.w);
                a0 = dot2(h0, wh[0][4*j+0], a0); a0 = dot2(h1, wh[0][4*j+1], a0);
                a0 = dot2(h2, wh[0][4*j+2], a0); a0 = dot2(h3, wh[0][4*j+3], a0);
                a1 = dot2(h0, wh[1][4*j+0], a1); a1 = dot2(h1, wh[1][4*j+1], a1);
                a1 = dot2(h2, wh[1][4*j+2], a1); a1 = dot2(h3, wh[1][4*j+3], a1);
                a2 = dot2(h0, wh[2][4*j+0], a2); a2 = dot2(h1, wh[2][4*j+1], a2);
                a2 = dot2(h2, wh[2][4*j+2], a2); a2 = dot2(h3, wh[2][4*j+3], a2);
                a3 = dot2(h0, wh[3][4*j+0], a3); a3 = dot2(h1, wh[3][4*j+1], a3);
                a3 = dot2(h2, wh[3][4*j+2], a3); a3 = dot2(h3, wh[3][4*j+3], a3);
            }
            const float4* xq = (const float4*)((const char*)x_lds[par] + 48 * ks);
            #pragma unroll
            for (int j = 0; j < 2; ++j) {
                float4 xv = xq[j];
                f16x2 x0 = __builtin_bit_cast(f16x2, xv.x);
                f16x2 x1 = __builtin_bit_cast(f16x2, xv.y);
                f16x2 x2 = __builtin_bit_cast(f16x2, xv.z);
                f16x2 x3 = __builtin_bit_cast(f16x2, xv.w);
                a0 = dot2(x0, wxr[0][4*j+0], a0); a0 = dot2(x1, wxr[0][4*j+1], a0);
                a0 = dot2(x2, wxr[0][4*j+2], a0); a0 = dot2(x3, wxr[0][4*j+3], a0);
                a1 = dot2(x0, wxr[1][4*j+0], a1); a1 = dot2(x1, wxr[1][4*j+1], a1);
                a1 = dot2(x2, wxr[1][4*j+2], a1); a1 = dot2(x3, wxr[1][4*j+3], a1);
                a2 = dot2(x0, wxr[2][4*j+0], a2); a2 = dot2(x1, wxr[2][4*j+1], a2);
                a2 = dot2(x2, wxr[2][4*j+2], a2); a2 = dot2(x3, wxr[2][4*j+3], a2);
                a3 = dot2(x0, wxr[3][4*j+0], a3); a3 = dot2(x1, wxr[3][4*j+1], a3);
                a3 = dot2(x2, wxr[3][4*j+2], a3); a3 = dot2(x3, wxr[3][4*j+3], a3);
            }
        }
        a0 += __shfl_xor(a0, 1); a0 += __shfl_xor(a0, 2);
        a1 += __shfl_xor(a1, 1); a1 += __shfl_xor(a1, 2);
        a2 += __shfl_xor(a2, 1); a2 += __shfl_xor(a2, 2);
        a3 += __shfl_xor(a3, 1); a3 += __shfl_xor(a3, 2);

        // activation + state (redundant, bit-identical in the 4 ks lanes)
        float ig = sigm(a0 + bq[0]);
        float fg = sigm(a1 + bq[1]);
        float gg = tanh_fast(a2 + bq[2]);
        float og = sigm(a3 + bq[3]);
        c_state = fg * c_state + ig * gg;
        float hval = og * tanh_fast(c_state);

        // publish own h-half: pack 2 units/uint, 64 agent stores of 4B
        _Float16 hf = (_Float16)hval;
        unsigned int hbits = (unsigned int)__builtin_bit_cast(unsigned short, hf);
        unsigned int hpair = hbits | (__shfl_down((int)hbits, 4) << 16);
        if ((tid & 7) == 0) {
            unsigned int* dst = (unsigned int*)(hxg + par * 256 + half * 128);
            __hip_atomic_store(&dst[u_loc >> 1], hpair,
                               __ATOMIC_RELAXED, __HIP_MEMORY_SCOPE_AGENT);
        }
        __syncthreads();  // B1: drains stores (vmcnt 0); h_lds now overwritable

        if (tid == 0) {
            __hip_atomic_fetch_add(&flg[par], 1, __ATOMIC_RELEASE, __HIP_MEMORY_SCOPE_AGENT);
            const int target = 2 * ((t >> 1) + 1);
            for (int spin = 0; spin < (1 << 26); ++spin) {
                if (__hip_atomic_load(&flg[par], __ATOMIC_ACQUIRE,
                                      __HIP_MEMORY_SCOPE_AGENT) >= target) break;
                __builtin_amdgcn_s_sleep(1);
            }
        }
        __syncthreads();  // B2: partner's h-half visible

        // stage h(t) into LDS: own half from regs, partner half from hx
        if (ks == 0) h_lds[u >> 6][u & 63] = (unsigned short)hbits;
        if (tid < 64) {
            const unsigned int* src = (const unsigned int*)(hxg + par * 256 + (half ^ 1) * 128);
            unsigned int v = __hip_atomic_load(&src[tid],
                                               __ATOMIC_RELAXED, __HIP_MEMORY_SCOPE_AGENT);
            int up = 128 * (half ^ 1) + 2 * tid;
            *(unsigned int*)&h_lds[up >> 6][up & 63] = v;
        }
        if (xload) {
            int d = tid - 448;
            _Float16 xv = (_Float16)x_next;
            x_lds[(t + 1) & 1][d >> 4][d & 15] = __builtin_bit_cast(unsigned short, xv);
        }
        __syncthreads();  // B3: h(t), x(t+1) staged

        // phase C: output projection (half==0 block only; waves 0..5)
        if (half == 0) {
            const int w = tid >> 6, l = tid & 63;
            if (w < Cc) {
                float p = 0.0f;
                #pragma unroll
                for (int j = 0; j < 4; ++j) {
                    unsigned short huu = h_lds[j][l];
                    _Float16 hh = __builtin_bit_cast(_Float16, huu);
                    p += (float)hh * wout_t[w][l + 64 * j];
                }
                #pragma unroll
                for (int off = 32; off > 0; off >>= 1) p += __shfl_down(p, off);
                if (l == 0) out[((long)g * Tt + t) * Cc + w] = p + bout_l[w];
            }
        }
    }
}

// ---------------- fallback (R2 kernel, if ws too small) ----------------
__global__ __launch_bounds__(1024) void lstm_fused(
    const float* __restrict__ x, const float* __restrict__ Wx,
    const float* __restrict__ Wh, const float* __restrict__ bias,
    const float* __restrict__ Wout, const float* __restrict__ bout,
    float* __restrict__ out)
{
    __shared__ float h_lds[Hh];
    __shared__ float gates_lds[G4];
    __shared__ float x_lds[2][Dd];
    __shared__ float wout_t[Cc][Hh];
    __shared__ float bout_l[Cc];
    const int tid = threadIdx.x;
    const int b   = blockIdx.x;
    float wx[Dd];
    #pragma unroll
    for (int d = 0; d < Dd; ++d) wx[d] = Wx[d * G4 + tid];
    const float bj = bias[tid];
    if (tid < Hh) h_lds[tid] = 0.0f;
    for (int i = tid; i < Cc * Hh; i += 1024) wout_t[i % Cc][i / Cc] = Wout[i];
    if (tid < Cc) bout_l[tid] = bout[tid];
    const float* xB = x + (long)b * Tt * Dd;
    if (tid < Dd) x_lds[0][tid] = xB[tid];
    float c_state = 0.0f;
    __syncthreads();
    const float* WhB = Wh + tid;
    for (int t = 0; t < Tt; ++t) {
        float gg = bj;
        const float* xr = x_lds[t & 1];
        #pragma unroll
        for (int d = 0; d < Dd; ++d) gg += xr[d] * wx[d];
        #pragma unroll 8
        for (int k = 0; k < Hh; ++k) gg += h_lds[k] * WhB[k * G4];
        float a;
        if (tid < 2 * Hh)      a = 1.0f / (1.0f + expf(-gg));
        else if (tid < 3 * Hh) a = tanhf(gg);
        else                   a = 1.0f / (1.0f + expf(-gg));
        gates_lds[tid] = a;
        __syncthreads();
        if (tid < Hh) {
            float iv = gates_lds[tid], fv = gates_lds[tid + Hh];
            float gv = gates_lds[tid + 2 * Hh], ov = gates_lds[tid + 3 * Hh];
            c_state = fv * c_state + iv * gv;
            h_lds[tid] = ov * tanhf(c_state);
        } else if (tid >= 384 && tid < 448) {
            int tn = t + 1;
            if (tn < Tt) x_lds[tn & 1][tid - 384] = xB[(long)tn * Dd + (tid - 384)];
        }
        __syncthreads();
        const int w = tid >> 6, l = tid & 63;
        if (w < Cc) {
            float p = 0.0f;
            #pragma unroll
            for (int qq = 0; qq < 4; ++qq) p += h_lds[l + 64 * qq] * wout_t[w][l + 64 * qq];
            #pragma unroll
            for (int off = 32; off > 0; off >>= 1) p += __shfl_down(p, off);
            if (l == 0) out[((long)b * Tt + t) * Cc + w] = p + bout_l[w];
        }
    }
}

extern "C" void kernel_launch(void* const* d_in, const int* in_sizes, int n_in,
                              void* d_out, int out_size, void* d_ws, size_t ws_size,
                              hipStream_t stream) {
    const float* x    = (const float*)d_in[0];
    const float* Wx   = (const float*)d_in[1];
    const float* Wh   = (const float*)d_in[2];
    const float* bvec = (const float*)d_in[3];
    const float* Wout = (const float*)d_in[4];
    const float* bout = (const float*)d_in[5];
    float* outp = (float*)d_out;

    if (ws_size >= (size_t)WS_NEED) {
        int* flags = (int*)d_ws;
        unsigned short* hx = (unsigned short*)((char*)d_ws + 1024);
        zero_flags<<<dim3(1), dim3(256), 0, stream>>>(flags);
        void* args[] = { (void*)&x, (void*)&Wx, (void*)&Wh, (void*)&bvec,
                         (void*)&Wout, (void*)&bout, (void*)&outp,
                         (void*)&flags, (void*)&hx };
        hipLaunchCooperativeKernel((void*)lstm_pair, dim3(256), dim3(512),
                                   args, 0, stream);
    } else {
        lstm_fused<<<dim3(128), dim3(1024), 0, stream>>>(x, Wx, Wh, bvec, Wout, bout, outp);
    }
}